// Round 2
// baseline (1785.245 us; speedup 1.0000x reference)
//
#include <hip/hip_runtime.h>
#include <hip/hip_bf16.h>

typedef unsigned short u16;
typedef __attribute__((ext_vector_type(8))) short bf16x8;
typedef __attribute__((ext_vector_type(4))) float f32x4;

static __device__ __forceinline__ u16 f2bf(float f) {
    union { float f; unsigned u; } cv; cv.f = f;
    unsigned u = cv.u;
    unsigned r = u + 0x7FFF + ((u >> 16) & 1);   // round-to-nearest-even
    return (u16)(r >> 16);
}
static __device__ __forceinline__ float bf2f(u16 b) {
    union { unsigned u; float f; } cv; cv.u = ((unsigned)b) << 16;
    return cv.f;
}
static __device__ __forceinline__ float sigmoidf_(float x) {
    return 1.0f / (1.0f + __expf(-x));
}

// ---------------------------------------------------------------------------
// Fuse Wf = wv @ wo (bf16, stored transposed [j][i]) and bfv = bv@wo + bo.
__global__ __launch_bounds__(256) void fuse_wvwo(
    const float* __restrict__ wv, const float* __restrict__ wo,
    const float* __restrict__ bv, const float* __restrict__ bo,
    u16* __restrict__ WfT, float* __restrict__ bfv)
{
    int j = blockIdx.x;
    int i = threadIdx.x;
    float s = 0.f;
    for (int k = 0; k < 256; ++k) s += wv[i * 256 + k] * wo[k * 256 + j];
    WfT[j * 256 + i] = f2bf(s);
    if (i == 0) {
        float t = bo[j];
        for (int k = 0; k < 256; ++k) t += bv[k] * wo[k * 256 + j];
        bfv[j] = t;
    }
}

// dst[n*K + k] = bf16(src[k*N + n])
__global__ __launch_bounds__(256) void transpose_bf(
    const float* __restrict__ src, u16* __restrict__ dst, int K, int N)
{
    long i = (long)blockIdx.x * 256 + threadIdx.x;
    if (i >= (long)K * N) return;
    int n = (int)(i / K), k = (int)(i % K);
    dst[i] = f2bf(src[(long)k * N + n]);
}

// ---------------------------------------------------------------------------
// Fused action-encoder + LayerNorm, MFMA version. 64 positions per block.
// kv = LN(relu(action@w1+b1) @ w2 + b2) -> bf16
__global__ __launch_bounds__(256) void ae_ln_mfma(
    const float* __restrict__ action,
    const float* __restrict__ w1, const float* __restrict__ b1,
    const u16* __restrict__ w2T, const float* __restrict__ b2,
    const float* __restrict__ g, const float* __restrict__ be,
    u16* __restrict__ kvbf)
{
    __shared__ u16 lB[256][136];   // w2T staged; reused as f32 [64][261] later
    __shared__ u16 lA[64][136];    // h1 tile bf16
    int tid = threadIdx.x;
    long base = (long)blockIdx.x * 64;

    for (int idx = tid; idx < 256 * 16; idx += 256) {
        int r = idx >> 4, ch = (idx & 15) * 8;
        *(uint4*)&lB[r][ch] = *(const uint4*)&w2T[r * 128 + ch];
    }
    for (int idx = tid; idx < 8192; idx += 256) {
        int r = idx >> 7, k = idx & 127;
        float a0 = action[(base + r) * 2], a1 = action[(base + r) * 2 + 1];
        float v = fmaf(a1, w1[128 + k], fmaf(a0, w1[k], b1[k]));
        lA[r][k] = f2bf(v > 0.f ? v : 0.f);
    }
    __syncthreads();

    int wv = tid >> 6, l = tid & 63;
    int fr = l & 15, fq = l >> 4;
    f32x4 acc[4][4] = {};
#pragma unroll
    for (int ks = 0; ks < 4; ++ks) {
        bf16x8 a[4], b[4];
#pragma unroll
        for (int mi = 0; mi < 4; ++mi) a[mi] = *(bf16x8*)&lA[mi * 16 + fr][ks * 32 + fq * 8];
#pragma unroll
        for (int ni = 0; ni < 4; ++ni) b[ni] = *(bf16x8*)&lB[wv * 64 + ni * 16 + fr][ks * 32 + fq * 8];
#pragma unroll
        for (int mi = 0; mi < 4; ++mi)
#pragma unroll
            for (int ni = 0; ni < 4; ++ni)
                acc[mi][ni] = __builtin_amdgcn_mfma_f32_16x16x32_bf16(a[mi], b[ni], acc[mi][ni], 0, 0, 0);
    }
    __syncthreads();

    float* e = (float*)&lB[0][0];   // [64][261] f32 scratch (66.8KB <= 69.6KB)
#pragma unroll
    for (int mi = 0; mi < 4; ++mi)
#pragma unroll
        for (int ni = 0; ni < 4; ++ni) {
            int col = wv * 64 + ni * 16 + fr;
            float bb = b2[col];
#pragma unroll
            for (int reg = 0; reg < 4; ++reg)
                e[(mi * 16 + fq * 4 + reg) * 261 + col] = acc[mi][ni][reg] + bb;
        }
    __syncthreads();

    int t = tid >> 2, sub = tid & 3;
    float s = 0.f, ss = 0.f;
#pragma unroll
    for (int i = 0; i < 64; ++i) {
        float v = e[t * 261 + sub + i * 4];
        s += v; ss += v * v;
    }
    s += __shfl_xor(s, 1); ss += __shfl_xor(ss, 1);
    s += __shfl_xor(s, 2); ss += __shfl_xor(ss, 2);
    float m = s * (1.f / 256.f);
    float var = ss * (1.f / 256.f) - m * m;
    float rs = rsqrtf(var + 1e-5f);
#pragma unroll
    for (int i8 = 0; i8 < 8; ++i8) {
        u16 pack[8];
#pragma unroll
        for (int j = 0; j < 8; ++j) {
            int col = sub * 64 + i8 * 8 + j;
            float v = (e[t * 261 + col] - m) * rs * g[col] + be[col];
            pack[j] = f2bf(v);
        }
        *(uint4*)&kvbf[(base + t) * 256 + sub * 64 + i8 * 8] = *(uint4*)pack;
    }
}

// ---------------------------------------------------------------------------
// Generic 64x64-tile bf16 GEMM:  C = A[M,K] @ BT[N,K]^T  (+bias[col]) (+modes)
template <int MODE>
__global__ __launch_bounds__(256) void gemm64(
    const u16* __restrict__ A, const u16* __restrict__ BT,
    const float* __restrict__ bias, const float* __restrict__ resid,
    u16* __restrict__ outBf, float* __restrict__ outF,
    int N, int K)
{
    __shared__ u16 lA[64][40];
    __shared__ u16 lB[64][40];
    int tid = threadIdx.x;
    int bm = blockIdx.x * 64, bn = blockIdx.y * 64;
    int srow = tid >> 2, sch = (tid & 3) * 8;

    f32x4 acc[2][2] = {};
    int w = tid >> 6, l = tid & 63;
    int wr = (w >> 1) * 32, wc = (w & 1) * 32;
    int fr = l & 15, fk = (l >> 4) * 8;

    for (int k0 = 0; k0 < K; k0 += 32) {
        *(uint4*)&lA[srow][sch] = *(const uint4*)&A[(long)(bm + srow) * K + k0 + sch];
        *(uint4*)&lB[srow][sch] = *(const uint4*)&BT[(long)(bn + srow) * K + k0 + sch];
        __syncthreads();
        bf16x8 a0 = *(bf16x8*)&lA[wr + fr][fk];
        bf16x8 a1 = *(bf16x8*)&lA[wr + 16 + fr][fk];
        bf16x8 b0 = *(bf16x8*)&lB[wc + fr][fk];
        bf16x8 b1 = *(bf16x8*)&lB[wc + 16 + fr][fk];
        acc[0][0] = __builtin_amdgcn_mfma_f32_16x16x32_bf16(a0, b0, acc[0][0], 0, 0, 0);
        acc[0][1] = __builtin_amdgcn_mfma_f32_16x16x32_bf16(a0, b1, acc[0][1], 0, 0, 0);
        acc[1][0] = __builtin_amdgcn_mfma_f32_16x16x32_bf16(a1, b0, acc[1][0], 0, 0, 0);
        acc[1][1] = __builtin_amdgcn_mfma_f32_16x16x32_bf16(a1, b1, acc[1][1], 0, 0, 0);
        __syncthreads();
    }

#pragma unroll
    for (int mi = 0; mi < 2; ++mi)
#pragma unroll
        for (int ni = 0; ni < 2; ++ni) {
            int c = bn + wc + ni * 16 + fr;
            float bz = bias[c];
#pragma unroll
            for (int reg = 0; reg < 4; ++reg) {
                int r = bm + wr + mi * 16 + (l >> 4) * 4 + reg;
                float v = acc[mi][ni][reg] + bz;
                if constexpr (MODE == 0) {
                    v += resid[(long)r * N + c];
                    outBf[(long)r * N + c] = f2bf(v);
                } else if constexpr (MODE == 1) {
                    outBf[(long)r * N + c] = f2bf(v);
                } else {
                    outF[(long)r * N + c] = v;
                    if ((r & 511) == 511) outF[8388608 + (long)(r >> 9) * N + c] = v;
                }
            }
        }
}

// ---------------------------------------------------------------------------
// Persistent GRU: 256 blocks = 16 t-groups x 16 col-groups, 384 threads.
// whh slice (96 N-rows x 512 K) lives in LDS for all 64 steps; h f32 carry
// lives in registers; A-fragments preloaded to regs (no K-loop barriers).
// Sync per step: 16-block t-group barrier via agent-scope atomics.
__global__ __launch_bounds__(384, 1) void gru_persistent(
    const u16* __restrict__ whhT, const float* __restrict__ bhh,
    const u16* __restrict__ gi_bf, const u16* __restrict__ h0_bf,
    u16* __restrict__ out_bf, unsigned* __restrict__ cnt)
{
    __shared__ u16 lw[96][520];     // whh slice, padded (+8 u16) rows
    __shared__ float ghs[32][100];  // gh exchange tile

    int tid = threadIdx.x;
    int bid = blockIdx.x;
    int tb = bid >> 4, cb = bid & 15;
    int tbase = tb * 32, cbase = cb * 32;

    // load whh slice: LDS row n_local = gate*32 + cc
    for (int idx = tid; idx < 96 * 64; idx += 384) {
        int r = idx >> 6, ch = (idx & 63) * 8;
        int gate = r >> 5, cc = r & 31;
        *(uint4*)&lw[r][ch] = *(const uint4*)&whhT[((size_t)(gate << 9) + cbase + cc) * 512 + ch];
    }

    int wv = tid >> 6;          // 0..5: 16 n-cols each
    int l = tid & 63;
    int fr = l & 15, fo = l >> 4;

    // epilogue assignment: elem i = tid + 384j -> (t = i>>5, c = i&31)
    float hreg[3] = {0.f, 0.f, 0.f};
    float bh_r[3], bh_z[3], bh_n[3];
    int erow[3], ecol[3]; bool ev[3];
#pragma unroll
    for (int j = 0; j < 3; ++j) {
        int i = tid + j * 384;
        ev[j] = (i < 1024);
        erow[j] = (i >> 5) & 31; ecol[j] = cbase + (i & 31);
        bh_r[j] = bh_z[j] = bh_n[j] = 0.f;
        if (ev[j]) {
            bh_r[j] = bhh[ecol[j]];
            bh_z[j] = bhh[512 + ecol[j]];
            bh_n[j] = bhh[1024 + ecol[j]];
        }
    }
    __syncthreads();

    for (int step = 0; step < 64; ++step) {
        const u16* hb = step ? out_bf + (size_t)(step - 1) * 512 * 512 : h0_bf;
        // A fragments -> regs (32 x 16B loads, L2/L3 resident)
        bf16x8 areg[16][2];
        const u16* ap = hb + (size_t)(tbase + fr) * 512 + fo * 8;
#pragma unroll
        for (int kk = 0; kk < 16; ++kk) {
            areg[kk][0] = *(const bf16x8*)(ap + kk * 32);
            areg[kk][1] = *(const bf16x8*)(ap + 16 * 512 + kk * 32);
        }
        f32x4 acc0 = {0.f, 0.f, 0.f, 0.f}, acc1 = acc0;
#pragma unroll
        for (int kk = 0; kk < 16; ++kk) {
            bf16x8 b = *(bf16x8*)&lw[wv * 16 + fr][kk * 32 + fo * 8];
            acc0 = __builtin_amdgcn_mfma_f32_16x16x32_bf16(areg[kk][0], b, acc0, 0, 0, 0);
            acc1 = __builtin_amdgcn_mfma_f32_16x16x32_bf16(areg[kk][1], b, acc1, 0, 0, 0);
        }
        int nl = wv * 16 + fr;
#pragma unroll
        for (int reg = 0; reg < 4; ++reg) {
            ghs[fo * 4 + reg][nl] = acc0[reg];
            ghs[16 + fo * 4 + reg][nl] = acc1[reg];
        }
        __syncthreads();

#pragma unroll
        for (int j = 0; j < 3; ++j) if (ev[j]) {
            int t = erow[j], col = ecol[j], c = col - cbase;
            size_t girow = ((size_t)step * 512 + tbase + t) * 1536;
            float gr = bf2f(gi_bf[girow + col]);
            float gz = bf2f(gi_bf[girow + 512 + col]);
            float gn = bf2f(gi_bf[girow + 1024 + col]);
            float rg = sigmoidf_(gr + ghs[t][c] + bh_r[j]);
            float zg = sigmoidf_(gz + ghs[t][32 + c] + bh_z[j]);
            float ng = tanhf(gn + rg * (ghs[t][64 + c] + bh_n[j]));
            float hn = (1.f - zg) * ng + zg * hreg[j];
            hreg[j] = hn;
            out_bf[((size_t)step * 512 + tbase + t) * 512 + col] = f2bf(hn);
        }
        __syncthreads();

        if (step < 63) {
            if (tid == 0) {
                __threadfence();  // release: drain + make h writes agent-visible
                __hip_atomic_fetch_add(&cnt[tb], 1u, __ATOMIC_RELAXED, __HIP_MEMORY_SCOPE_AGENT);
                unsigned tgt = 16u * (unsigned)(step + 1);
                while (__hip_atomic_load(&cnt[tb], __ATOMIC_RELAXED, __HIP_MEMORY_SCOPE_AGENT) < tgt)
                    __builtin_amdgcn_s_sleep(1);
                __threadfence();  // acquire: invalidate L1/L2 before next A reads
            }
            __syncthreads();
        }
    }
}

// ---------------------------------------------------------------------------
extern "C" void kernel_launch(void* const* d_in, const int* in_sizes, int n_in,
                              void* d_out, int out_size, void* d_ws, size_t ws_size,
                              hipStream_t stream)
{
    const float* action  = (const float*)d_in[1];
    const float* ae_w1   = (const float*)d_in[2];
    const float* ae_b1   = (const float*)d_in[3];
    const float* ae_w2   = (const float*)d_in[4];
    const float* ae_b2   = (const float*)d_in[5];
    const float* state   = (const float*)d_in[0];
    const float* ln2_g   = (const float*)d_in[8];
    const float* ln2_b   = (const float*)d_in[9];
    const float* wv      = (const float*)d_in[14];
    const float* bv      = (const float*)d_in[15];
    const float* wo      = (const float*)d_in[16];
    const float* bo      = (const float*)d_in[17];
    const float* gru_wih = (const float*)d_in[18];
    const float* gru_bih = (const float*)d_in[19];
    const float* gru_whh = (const float*)d_in[20];
    const float* gru_bhh = (const float*)d_in[21];
    const float* mlp_w   = (const float*)d_in[22];
    const float* mlp_b   = (const float*)d_in[23];

    char* ws = (char*)d_ws;
    size_t off = 0;
    auto carve = [&](size_t bytes) -> char* {
        char* p = ws + off; off = (off + bytes + 255) & ~(size_t)255; return p;
    };
    u16*   kv_bf  = (u16*)carve(32768ull * 256 * 2);
    u16*   x_bf   = (u16*)carve(32768ull * 256 * 2);
    u16*   gi_bf  = (u16*)carve(32768ull * 1536 * 2);
    u16*   out_bf = (u16*)carve(32768ull * 512 * 2);
    u16*   WfT    = (u16*)carve(256 * 256 * 2);
    float* bfv    = (float*)carve(256 * 4);
    u16*   wihT   = (u16*)carve(1536 * 256 * 2);
    u16*   whhT   = (u16*)carve(1536 * 512 * 2);
    u16*   mlpT   = (u16*)carve(256 * 512 * 2);
    u16*   w2T    = (u16*)carve(256 * 128 * 2);
    u16*   h0_bf  = (u16*)carve(512 * 512 * 2);
    unsigned* cnt = (unsigned*)carve(64 * 4);

    hipMemsetAsync(h0_bf, 0, 512 * 512 * 2, stream);
    hipMemsetAsync(cnt, 0, 64 * 4, stream);

    fuse_wvwo<<<256, 256, 0, stream>>>(wv, wo, bv, bo, WfT, bfv);
    transpose_bf<<<1536, 256, 0, stream>>>(gru_wih, wihT, 256, 1536);
    transpose_bf<<<3072, 256, 0, stream>>>(gru_whh, whhT, 512, 1536);
    transpose_bf<<<512, 256, 0, stream>>>(mlp_w, mlpT, 512, 256);
    transpose_bf<<<128, 256, 0, stream>>>(ae_w2, w2T, 128, 256);

    ae_ln_mfma<<<512, 256, 0, stream>>>(action, ae_w1, ae_b1, w2T, ae_b2,
                                        ln2_g, ln2_b, kv_bf);

    // x = state + kv_in @ Wf + bfv   (bf16 out)
    gemm64<0><<<dim3(512, 4), 256, 0, stream>>>(kv_bf, WfT, bfv, state, x_bf, nullptr, 256, 256);
    // gi = x @ wih + bih             (bf16 out)
    gemm64<1><<<dim3(512, 24), 256, 0, stream>>>(x_bf, wihT, gru_bih, nullptr, gi_bf, nullptr, 1536, 256);

    // GRU: one persistent cooperative kernel, all 64 steps
    {
        void* args[] = { (void*)&whhT, (void*)&gru_bhh, (void*)&gi_bf,
                         (void*)&h0_bf, (void*)&out_bf, (void*)&cnt };
        hipLaunchCooperativeKernel((const void*)gru_persistent, dim3(256), dim3(384),
                                   args, 0, stream);
    }

    // states = out @ mlp_w + mlp_b   (f32 out + last-row duplicate)
    gemm64<2><<<dim3(512, 4), 256, 0, stream>>>(out_bf, mlpT, mlp_b, nullptr, nullptr,
                                                (float*)d_out, 256, 512);
}

// Round 3
// 834.152 us; speedup vs baseline: 2.1402x; 2.1402x over previous
//
#include <hip/hip_runtime.h>
#include <hip/hip_bf16.h>

typedef unsigned short u16;
typedef __attribute__((ext_vector_type(8))) short bf16x8;
typedef __attribute__((ext_vector_type(4))) float f32x4;

static __device__ __forceinline__ u16 f2bf(float f) {
    union { float f; unsigned u; } cv; cv.f = f;
    unsigned u = cv.u;
    unsigned r = u + 0x7FFF + ((u >> 16) & 1);   // round-to-nearest-even
    return (u16)(r >> 16);
}
static __device__ __forceinline__ float bf2f(u16 b) {
    union { unsigned u; float f; } cv; cv.u = ((unsigned)b) << 16;
    return cv.f;
}
static __device__ __forceinline__ float sigmoidf_(float x) {
    return 1.0f / (1.0f + __expf(-x));
}

// ---------------------------------------------------------------------------
// Fuse Wf = wv @ wo (bf16, stored transposed [j][i]) and bfv = bv@wo + bo.
__global__ __launch_bounds__(256) void fuse_wvwo(
    const float* __restrict__ wv, const float* __restrict__ wo,
    const float* __restrict__ bv, const float* __restrict__ bo,
    u16* __restrict__ WfT, float* __restrict__ bfv)
{
    int j = blockIdx.x;
    int i = threadIdx.x;
    float s = 0.f;
    for (int k = 0; k < 256; ++k) s += wv[i * 256 + k] * wo[k * 256 + j];
    WfT[j * 256 + i] = f2bf(s);
    if (i == 0) {
        float t = bo[j];
        for (int k = 0; k < 256; ++k) t += bv[k] * wo[k * 256 + j];
        bfv[j] = t;
    }
}

// dst[n*K + k] = bf16(src[k*N + n])
__global__ __launch_bounds__(256) void transpose_bf(
    const float* __restrict__ src, u16* __restrict__ dst, int K, int N)
{
    long i = (long)blockIdx.x * 256 + threadIdx.x;
    if (i >= (long)K * N) return;
    int n = (int)(i / K), k = (int)(i % K);
    dst[i] = f2bf(src[(long)k * N + n]);
}

// ---------------------------------------------------------------------------
// Fused action-encoder + LayerNorm, MFMA version. 64 positions per block.
__global__ __launch_bounds__(256) void ae_ln_mfma(
    const float* __restrict__ action,
    const float* __restrict__ w1, const float* __restrict__ b1,
    const u16* __restrict__ w2T, const float* __restrict__ b2,
    const float* __restrict__ g, const float* __restrict__ be,
    u16* __restrict__ kvbf)
{
    __shared__ u16 lB[256][136];   // w2T staged; reused as f32 [64][261] later
    __shared__ u16 lA[64][136];    // h1 tile bf16
    int tid = threadIdx.x;
    long base = (long)blockIdx.x * 64;

    for (int idx = tid; idx < 256 * 16; idx += 256) {
        int r = idx >> 4, ch = (idx & 15) * 8;
        *(uint4*)&lB[r][ch] = *(const uint4*)&w2T[r * 128 + ch];
    }
    for (int idx = tid; idx < 8192; idx += 256) {
        int r = idx >> 7, k = idx & 127;
        float a0 = action[(base + r) * 2], a1 = action[(base + r) * 2 + 1];
        float v = fmaf(a1, w1[128 + k], fmaf(a0, w1[k], b1[k]));
        lA[r][k] = f2bf(v > 0.f ? v : 0.f);
    }
    __syncthreads();

    int wv = tid >> 6, l = tid & 63;
    int fr = l & 15, fq = l >> 4;
    f32x4 acc[4][4] = {};
#pragma unroll
    for (int ks = 0; ks < 4; ++ks) {
        bf16x8 a[4], b[4];
#pragma unroll
        for (int mi = 0; mi < 4; ++mi) a[mi] = *(bf16x8*)&lA[mi * 16 + fr][ks * 32 + fq * 8];
#pragma unroll
        for (int ni = 0; ni < 4; ++ni) b[ni] = *(bf16x8*)&lB[wv * 64 + ni * 16 + fr][ks * 32 + fq * 8];
#pragma unroll
        for (int mi = 0; mi < 4; ++mi)
#pragma unroll
            for (int ni = 0; ni < 4; ++ni)
                acc[mi][ni] = __builtin_amdgcn_mfma_f32_16x16x32_bf16(a[mi], b[ni], acc[mi][ni], 0, 0, 0);
    }
    __syncthreads();

    float* e = (float*)&lB[0][0];   // [64][261] f32 scratch
#pragma unroll
    for (int mi = 0; mi < 4; ++mi)
#pragma unroll
        for (int ni = 0; ni < 4; ++ni) {
            int col = wv * 64 + ni * 16 + fr;
            float bb = b2[col];
#pragma unroll
            for (int reg = 0; reg < 4; ++reg)
                e[(mi * 16 + fq * 4 + reg) * 261 + col] = acc[mi][ni][reg] + bb;
        }
    __syncthreads();

    int t = tid >> 2, sub = tid & 3;
    float s = 0.f, ss = 0.f;
#pragma unroll
    for (int i = 0; i < 64; ++i) {
        float v = e[t * 261 + sub + i * 4];
        s += v; ss += v * v;
    }
    s += __shfl_xor(s, 1); ss += __shfl_xor(ss, 1);
    s += __shfl_xor(s, 2); ss += __shfl_xor(ss, 2);
    float m = s * (1.f / 256.f);
    float var = ss * (1.f / 256.f) - m * m;
    float rs = rsqrtf(var + 1e-5f);
#pragma unroll
    for (int i8 = 0; i8 < 8; ++i8) {
        u16 pack[8];
#pragma unroll
        for (int j = 0; j < 8; ++j) {
            int col = sub * 64 + i8 * 8 + j;
            float v = (e[t * 261 + col] - m) * rs * g[col] + be[col];
            pack[j] = f2bf(v);
        }
        *(uint4*)&kvbf[(base + t) * 256 + sub * 64 + i8 * 8] = *(uint4*)pack;
    }
}

// ---------------------------------------------------------------------------
// Generic 64x64-tile bf16 GEMM:  C = A[M,K] @ BT[N,K]^T  (+bias[col]) (+modes)
template <int MODE>
__global__ __launch_bounds__(256) void gemm64(
    const u16* __restrict__ A, const u16* __restrict__ BT,
    const float* __restrict__ bias, const float* __restrict__ resid,
    u16* __restrict__ outBf, float* __restrict__ outF,
    int N, int K)
{
    __shared__ u16 lA[64][40];
    __shared__ u16 lB[64][40];
    int tid = threadIdx.x;
    int bm = blockIdx.x * 64, bn = blockIdx.y * 64;
    int srow = tid >> 2, sch = (tid & 3) * 8;

    f32x4 acc[2][2] = {};
    int w = tid >> 6, l = tid & 63;
    int wr = (w >> 1) * 32, wc = (w & 1) * 32;
    int fr = l & 15, fk = (l >> 4) * 8;

    for (int k0 = 0; k0 < K; k0 += 32) {
        *(uint4*)&lA[srow][sch] = *(const uint4*)&A[(long)(bm + srow) * K + k0 + sch];
        *(uint4*)&lB[srow][sch] = *(const uint4*)&BT[(long)(bn + srow) * K + k0 + sch];
        __syncthreads();
        bf16x8 a0 = *(bf16x8*)&lA[wr + fr][fk];
        bf16x8 a1 = *(bf16x8*)&lA[wr + 16 + fr][fk];
        bf16x8 b0 = *(bf16x8*)&lB[wc + fr][fk];
        bf16x8 b1 = *(bf16x8*)&lB[wc + 16 + fr][fk];
        acc[0][0] = __builtin_amdgcn_mfma_f32_16x16x32_bf16(a0, b0, acc[0][0], 0, 0, 0);
        acc[0][1] = __builtin_amdgcn_mfma_f32_16x16x32_bf16(a0, b1, acc[0][1], 0, 0, 0);
        acc[1][0] = __builtin_amdgcn_mfma_f32_16x16x32_bf16(a1, b0, acc[1][0], 0, 0, 0);
        acc[1][1] = __builtin_amdgcn_mfma_f32_16x16x32_bf16(a1, b1, acc[1][1], 0, 0, 0);
        __syncthreads();
    }

#pragma unroll
    for (int mi = 0; mi < 2; ++mi)
#pragma unroll
        for (int ni = 0; ni < 2; ++ni) {
            int c = bn + wc + ni * 16 + fr;
            float bz = bias[c];
#pragma unroll
            for (int reg = 0; reg < 4; ++reg) {
                int r = bm + wr + mi * 16 + (l >> 4) * 4 + reg;
                float v = acc[mi][ni][reg] + bz;
                if constexpr (MODE == 0) {
                    v += resid[(long)r * N + c];
                    outBf[(long)r * N + c] = f2bf(v);
                } else if constexpr (MODE == 1) {
                    outBf[(long)r * N + c] = f2bf(v);
                } else {
                    outF[(long)r * N + c] = v;
                    if ((r & 511) == 511) outF[8388608 + (long)(r >> 9) * N + c] = v;
                }
            }
        }
}

// ---------------------------------------------------------------------------
// One GRU step, barrier-free. Grid (16 cb, 16 tb), 256 threads = 4 waves.
// Wave w: t-rows tbase+(w&1)*16..+16, cols cbase+(w>>1)*16..+16, ALL 3 gates
// in registers. A (prev h) and B (whh) fragments read directly from L2.
__global__ __launch_bounds__(256) void gru_step2(
    const u16* __restrict__ hb,      // prev h bf16 [512][512]
    const u16* __restrict__ whhT,    // [1536][512] (gate*512+col major)
    const float* __restrict__ bhh,   // [1536]
    const u16* __restrict__ gi_step, // gi for this step [512][1536]
    float* __restrict__ h_f,         // f32 carry [512][512] (in/out)
    u16* __restrict__ hout)          // this step's h bf16 [512][512]
{
    int tid = threadIdx.x;
    int w = tid >> 6, l = tid & 63;
    int cbase = blockIdx.x * 32, tbase = blockIdx.y * 32;
    int fr = l & 15, fo = l >> 4;
    int thalf = (w & 1) * 16, csub = (w >> 1) * 16;

    const u16* ap = hb + (size_t)(tbase + thalf + fr) * 512 + fo * 8;
    const u16* bp0 = whhT + ((size_t)(cbase + csub + fr)) * 512 + fo * 8;
    const u16* bp1 = bp0 + (size_t)512 * 512;
    const u16* bp2 = bp1 + (size_t)512 * 512;

    f32x4 acc0 = {0.f, 0.f, 0.f, 0.f}, acc1 = acc0, acc2 = acc0;
#pragma unroll
    for (int kk = 0; kk < 16; ++kk) {
        bf16x8 a  = *(const bf16x8*)(ap + kk * 32);
        bf16x8 b0 = *(const bf16x8*)(bp0 + kk * 32);
        bf16x8 b1 = *(const bf16x8*)(bp1 + kk * 32);
        bf16x8 b2 = *(const bf16x8*)(bp2 + kk * 32);
        acc0 = __builtin_amdgcn_mfma_f32_16x16x32_bf16(a, b0, acc0, 0, 0, 0);
        acc1 = __builtin_amdgcn_mfma_f32_16x16x32_bf16(a, b1, acc1, 0, 0, 0);
        acc2 = __builtin_amdgcn_mfma_f32_16x16x32_bf16(a, b2, acc2, 0, 0, 0);
    }

    int col = cbase + csub + fr;
    float bh_r = bhh[col], bh_z = bhh[512 + col], bh_n = bhh[1024 + col];
#pragma unroll
    for (int reg = 0; reg < 4; ++reg) {
        int t = tbase + thalf + fo * 4 + reg;
        size_t girow = (size_t)t * 1536;
        float gr = bf2f(gi_step[girow + col]);
        float gz = bf2f(gi_step[girow + 512 + col]);
        float gn = bf2f(gi_step[girow + 1024 + col]);
        float rg = sigmoidf_(gr + acc0[reg] + bh_r);
        float zg = sigmoidf_(gz + acc1[reg] + bh_z);
        float ng = tanhf(gn + rg * (acc2[reg] + bh_n));
        float hp = h_f[(size_t)t * 512 + col];
        float hn = (1.f - zg) * ng + zg * hp;
        h_f[(size_t)t * 512 + col] = hn;
        hout[(size_t)t * 512 + col] = f2bf(hn);
    }
}

// ---------------------------------------------------------------------------
extern "C" void kernel_launch(void* const* d_in, const int* in_sizes, int n_in,
                              void* d_out, int out_size, void* d_ws, size_t ws_size,
                              hipStream_t stream)
{
    const float* state   = (const float*)d_in[0];
    const float* action  = (const float*)d_in[1];
    const float* ae_w1   = (const float*)d_in[2];
    const float* ae_b1   = (const float*)d_in[3];
    const float* ae_w2   = (const float*)d_in[4];
    const float* ae_b2   = (const float*)d_in[5];
    const float* ln2_g   = (const float*)d_in[8];
    const float* ln2_b   = (const float*)d_in[9];
    const float* wv      = (const float*)d_in[14];
    const float* bv      = (const float*)d_in[15];
    const float* wo      = (const float*)d_in[16];
    const float* bo      = (const float*)d_in[17];
    const float* gru_wih = (const float*)d_in[18];
    const float* gru_bih = (const float*)d_in[19];
    const float* gru_whh = (const float*)d_in[20];
    const float* gru_bhh = (const float*)d_in[21];
    const float* mlp_w   = (const float*)d_in[22];
    const float* mlp_b   = (const float*)d_in[23];

    char* ws = (char*)d_ws;
    size_t off = 0;
    auto carve = [&](size_t bytes) -> char* {
        char* p = ws + off; off = (off + bytes + 255) & ~(size_t)255; return p;
    };
    u16*   kv_bf  = (u16*)carve(32768ull * 256 * 2);
    u16*   x_bf   = (u16*)carve(32768ull * 256 * 2);
    u16*   gi_bf  = (u16*)carve(32768ull * 1536 * 2);
    u16*   out_bf = (u16*)carve(32768ull * 512 * 2);
    u16*   WfT    = (u16*)carve(256 * 256 * 2);
    float* bfv    = (float*)carve(256 * 4);
    u16*   wihT   = (u16*)carve(1536 * 256 * 2);
    u16*   whhT   = (u16*)carve(1536 * 512 * 2);
    u16*   mlpT   = (u16*)carve(256 * 512 * 2);
    u16*   w2T    = (u16*)carve(256 * 128 * 2);
    u16*   h0_bf  = (u16*)carve(512 * 512 * 2);
    float* h_f    = (float*)carve(512 * 512 * 4);

    hipMemsetAsync(h0_bf, 0, 512 * 512 * 2, stream);
    hipMemsetAsync(h_f, 0, 512 * 512 * 4, stream);

    fuse_wvwo<<<256, 256, 0, stream>>>(wv, wo, bv, bo, WfT, bfv);
    transpose_bf<<<1536, 256, 0, stream>>>(gru_wih, wihT, 256, 1536);
    transpose_bf<<<3072, 256, 0, stream>>>(gru_whh, whhT, 512, 1536);
    transpose_bf<<<512, 256, 0, stream>>>(mlp_w, mlpT, 512, 256);
    transpose_bf<<<128, 256, 0, stream>>>(ae_w2, w2T, 128, 256);

    ae_ln_mfma<<<512, 256, 0, stream>>>(action, ae_w1, ae_b1, w2T, ae_b2,
                                        ln2_g, ln2_b, kv_bf);

    // x = state + kv_in @ Wf + bfv   (bf16 out)
    gemm64<0><<<dim3(512, 4), 256, 0, stream>>>(kv_bf, WfT, bfv, state, x_bf, nullptr, 256, 256);
    // gi = x @ wih + bih             (bf16 out)
    gemm64<1><<<dim3(512, 24), 256, 0, stream>>>(x_bf, wihT, gru_bih, nullptr, gi_bf, nullptr, 1536, 256);

    // GRU: 64 lightweight barrier-free step kernels
    for (int b = 0; b < 64; ++b) {
        const u16* hb = b ? out_bf + (size_t)(b - 1) * 512 * 512 : h0_bf;
        gru_step2<<<dim3(16, 16), 256, 0, stream>>>(
            hb, whhT, gru_bhh, gi_bf + (size_t)b * 512 * 1536,
            h_f, out_bf + (size_t)b * 512 * 512);
    }

    // states = out @ mlp_w + mlp_b   (f32 out + last-row duplicate)
    gemm64<2><<<dim3(512, 4), 256, 0, stream>>>(out_bf, mlpT, mlp_b, nullptr, nullptr,
                                                (float*)d_out, 256, 512);
}

// Round 4
// 510.680 us; speedup vs baseline: 3.4958x; 1.6334x over previous
//
#include <hip/hip_runtime.h>
#include <hip/hip_bf16.h>

typedef unsigned short u16;
typedef __attribute__((ext_vector_type(8))) short bf16x8;
typedef __attribute__((ext_vector_type(4))) float f32x4;

static __device__ __forceinline__ u16 f2bf(float f) {
    union { float f; unsigned u; } cv; cv.f = f;
    unsigned u = cv.u;
    unsigned r = u + 0x7FFF + ((u >> 16) & 1);   // round-to-nearest-even
    return (u16)(r >> 16);
}
static __device__ __forceinline__ float bf2f(u16 b) {
    union { unsigned u; float f; } cv; cv.u = ((unsigned)b) << 16;
    return cv.f;
}
static __device__ __forceinline__ float sigmoidf_(float x) {
    return 1.0f / (1.0f + __expf(-x));
}

// ---------------------------------------------------------------------------
// Fuse Wf = wv @ wo (bf16, stored transposed [j][i]) and bfv = bv@wo + bo.
__global__ __launch_bounds__(256) void fuse_wvwo(
    const float* __restrict__ wv, const float* __restrict__ wo,
    const float* __restrict__ bv, const float* __restrict__ bo,
    u16* __restrict__ WfT, float* __restrict__ bfv)
{
    int j = blockIdx.x;
    int i = threadIdx.x;
    float s = 0.f;
    for (int k = 0; k < 256; ++k) s += wv[i * 256 + k] * wo[k * 256 + j];
    WfT[j * 256 + i] = f2bf(s);
    if (i == 0) {
        float t = bo[j];
        for (int k = 0; k < 256; ++k) t += bv[k] * wo[k * 256 + j];
        bfv[j] = t;
    }
}

// dst[n*K + k] = bf16(src[k*N + n])
__global__ __launch_bounds__(256) void transpose_bf(
    const float* __restrict__ src, u16* __restrict__ dst, int K, int N)
{
    long i = (long)blockIdx.x * 256 + threadIdx.x;
    if (i >= (long)K * N) return;
    int n = (int)(i / K), k = (int)(i % K);
    dst[i] = f2bf(src[(long)k * N + n]);
}

// ---------------------------------------------------------------------------
// Fused action-encoder + LayerNorm, MFMA version. 64 positions per block.
__global__ __launch_bounds__(256) void ae_ln_mfma(
    const float* __restrict__ action,
    const float* __restrict__ w1, const float* __restrict__ b1,
    const u16* __restrict__ w2T, const float* __restrict__ b2,
    const float* __restrict__ g, const float* __restrict__ be,
    u16* __restrict__ kvbf)
{
    __shared__ u16 lB[256][136];   // w2T staged; reused as f32 [64][261] later
    __shared__ u16 lA[64][136];    // h1 tile bf16
    int tid = threadIdx.x;
    long base = (long)blockIdx.x * 64;

    for (int idx = tid; idx < 256 * 16; idx += 256) {
        int r = idx >> 4, ch = (idx & 15) * 8;
        *(uint4*)&lB[r][ch] = *(const uint4*)&w2T[r * 128 + ch];
    }
    for (int idx = tid; idx < 8192; idx += 256) {
        int r = idx >> 7, k = idx & 127;
        float a0 = action[(base + r) * 2], a1 = action[(base + r) * 2 + 1];
        float v = fmaf(a1, w1[128 + k], fmaf(a0, w1[k], b1[k]));
        lA[r][k] = f2bf(v > 0.f ? v : 0.f);
    }
    __syncthreads();

    int wv = tid >> 6, l = tid & 63;
    int fr = l & 15, fq = l >> 4;
    f32x4 acc[4][4] = {};
#pragma unroll
    for (int ks = 0; ks < 4; ++ks) {
        bf16x8 a[4], b[4];
#pragma unroll
        for (int mi = 0; mi < 4; ++mi) a[mi] = *(bf16x8*)&lA[mi * 16 + fr][ks * 32 + fq * 8];
#pragma unroll
        for (int ni = 0; ni < 4; ++ni) b[ni] = *(bf16x8*)&lB[wv * 64 + ni * 16 + fr][ks * 32 + fq * 8];
#pragma unroll
        for (int mi = 0; mi < 4; ++mi)
#pragma unroll
            for (int ni = 0; ni < 4; ++ni)
                acc[mi][ni] = __builtin_amdgcn_mfma_f32_16x16x32_bf16(a[mi], b[ni], acc[mi][ni], 0, 0, 0);
    }
    __syncthreads();

    float* e = (float*)&lB[0][0];   // [64][261] f32 scratch
#pragma unroll
    for (int mi = 0; mi < 4; ++mi)
#pragma unroll
        for (int ni = 0; ni < 4; ++ni) {
            int col = wv * 64 + ni * 16 + fr;
            float bb = b2[col];
#pragma unroll
            for (int reg = 0; reg < 4; ++reg)
                e[(mi * 16 + fq * 4 + reg) * 261 + col] = acc[mi][ni][reg] + bb;
        }
    __syncthreads();

    int t = tid >> 2, sub = tid & 3;
    float s = 0.f, ss = 0.f;
#pragma unroll
    for (int i = 0; i < 64; ++i) {
        float v = e[t * 261 + sub + i * 4];
        s += v; ss += v * v;
    }
    s += __shfl_xor(s, 1); ss += __shfl_xor(ss, 1);
    s += __shfl_xor(s, 2); ss += __shfl_xor(ss, 2);
    float m = s * (1.f / 256.f);
    float var = ss * (1.f / 256.f) - m * m;
    float rs = rsqrtf(var + 1e-5f);
#pragma unroll
    for (int i8 = 0; i8 < 8; ++i8) {
        u16 pack[8];
#pragma unroll
        for (int j = 0; j < 8; ++j) {
            int col = sub * 64 + i8 * 8 + j;
            float v = (e[t * 261 + col] - m) * rs * g[col] + be[col];
            pack[j] = f2bf(v);
        }
        *(uint4*)&kvbf[(base + t) * 256 + sub * 64 + i8 * 8] = *(uint4*)pack;
    }
}

// ---------------------------------------------------------------------------
// Generic 64x64-tile bf16 GEMM:  C = A[M,K] @ BT[N,K]^T  (+bias[col]) (+modes)
template <int MODE>
__global__ __launch_bounds__(256) void gemm64(
    const u16* __restrict__ A, const u16* __restrict__ BT,
    const float* __restrict__ bias, const float* __restrict__ resid,
    u16* __restrict__ outBf, float* __restrict__ outF,
    int N, int K)
{
    __shared__ u16 lA[64][40];
    __shared__ u16 lB[64][40];
    int tid = threadIdx.x;
    int bm = blockIdx.x * 64, bn = blockIdx.y * 64;
    int srow = tid >> 2, sch = (tid & 3) * 8;

    f32x4 acc[2][2] = {};
    int w = tid >> 6, l = tid & 63;
    int wr = (w >> 1) * 32, wc = (w & 1) * 32;
    int fr = l & 15, fk = (l >> 4) * 8;

    for (int k0 = 0; k0 < K; k0 += 32) {
        *(uint4*)&lA[srow][sch] = *(const uint4*)&A[(long)(bm + srow) * K + k0 + sch];
        *(uint4*)&lB[srow][sch] = *(const uint4*)&BT[(long)(bn + srow) * K + k0 + sch];
        __syncthreads();
        bf16x8 a0 = *(bf16x8*)&lA[wr + fr][fk];
        bf16x8 a1 = *(bf16x8*)&lA[wr + 16 + fr][fk];
        bf16x8 b0 = *(bf16x8*)&lB[wc + fr][fk];
        bf16x8 b1 = *(bf16x8*)&lB[wc + 16 + fr][fk];
        acc[0][0] = __builtin_amdgcn_mfma_f32_16x16x32_bf16(a0, b0, acc[0][0], 0, 0, 0);
        acc[0][1] = __builtin_amdgcn_mfma_f32_16x16x32_bf16(a0, b1, acc[0][1], 0, 0, 0);
        acc[1][0] = __builtin_amdgcn_mfma_f32_16x16x32_bf16(a1, b0, acc[1][0], 0, 0, 0);
        acc[1][1] = __builtin_amdgcn_mfma_f32_16x16x32_bf16(a1, b1, acc[1][1], 0, 0, 0);
        __syncthreads();
    }

#pragma unroll
    for (int mi = 0; mi < 2; ++mi)
#pragma unroll
        for (int ni = 0; ni < 2; ++ni) {
            int c = bn + wc + ni * 16 + fr;
            float bz = bias[c];
#pragma unroll
            for (int reg = 0; reg < 4; ++reg) {
                int r = bm + wr + mi * 16 + (l >> 4) * 4 + reg;
                float v = acc[mi][ni][reg] + bz;
                if constexpr (MODE == 0) {
                    v += resid[(long)r * N + c];
                    outBf[(long)r * N + c] = f2bf(v);
                } else if constexpr (MODE == 1) {
                    outBf[(long)r * N + c] = f2bf(v);
                } else {
                    outF[(long)r * N + c] = v;
                    if ((r & 511) == 511) outF[8388608 + (long)(r >> 9) * N + c] = v;
                }
            }
        }
}

// ---------------------------------------------------------------------------
// Persistent GRU v2. 256 blocks = 16 t-groups x 16 col-blocks, 768 threads
// (12 waves). whh slice (96 gate-cols x 512) LDS-resident for all 64 steps.
// h exchange via agent-scope relaxed atomics (sc0/sc1: write-through L3,
// read-bypass L2) -- NO cache-flushing fences anywhere. Per-step sync:
// per-t-group counter (release by vmcnt-drain at __syncthreads + in-order add).
__global__ __launch_bounds__(768, 1) void gru_persistent2(
    const u16* __restrict__ whhT, const float* __restrict__ bhh,
    const u16* __restrict__ gi_bf, const u16* __restrict__ h0_bf,
    u16* __restrict__ out_bf, unsigned* __restrict__ cnt)
{
    __shared__ u16 lw[96][520];     // whh slice (99.8 KB), +8 pad
    __shared__ u16 lhA[32][520];    // h tile (33.3 KB), +8 pad
    __shared__ float ghs[32][100];  // gate partials (12.8 KB)

    int tid = threadIdx.x;
    int bid = blockIdx.x;
    int tg = bid >> 4, cb = bid & 15;
    int tbase = tg * 32, cbase = cb * 32;

    // stage whh slice once: lw row = gate*32 + cc
    for (int idx = tid; idx < 96 * 64; idx += 768) {
        int r = idx >> 6, ch = (idx & 63) * 8;
        int gate = r >> 5, cc = r & 31;
        *(uint4*)&lw[r][ch] = *(const uint4*)&whhT[((size_t)(gate << 9) + cbase + cc) * 512 + ch];
    }

    int w = tid >> 6, l = tid & 63;
    int fr = l & 15, fo = l >> 4;
    int th = w & 1, ct = w >> 1;    // wave tile: t-half, gate-col tile (0..5)

    // epilogue: threads 0..511 own 2 h-columns of one t-row
    int et = tid >> 4;
    int ec = (tid & 15) * 2;
    bool ep = tid < 512;
    float hreg0 = 0.f, hreg1 = 0.f;
    float bh_r0 = 0, bh_r1 = 0, bh_z0 = 0, bh_z1 = 0, bh_n0 = 0, bh_n1 = 0;
    if (ep) {
        bh_r0 = bhh[cbase + ec];        bh_r1 = bhh[cbase + ec + 1];
        bh_z0 = bhh[512 + cbase + ec];  bh_z1 = bhh[512 + cbase + ec + 1];
        bh_n0 = bhh[1024 + cbase + ec]; bh_n1 = bhh[1024 + cbase + ec + 1];
    }
    __syncthreads();

    for (int step = 0; step < 64; ++step) {
        // ---- stage this t-group's h rows (32x512 bf16) from L3 ----
        const unsigned long long* hb64 = (const unsigned long long*)
            (step ? out_bf + (size_t)(step - 1) * 262144 : h0_bf);
        for (int idx = tid; idx < 4096; idx += 768) {
            int r = idx >> 7, kw = idx & 127;
            unsigned long long v = __hip_atomic_load(
                hb64 + (size_t)(tbase + r) * 128 + kw,
                __ATOMIC_RELAXED, __HIP_MEMORY_SCOPE_AGENT);
            *(unsigned long long*)&lhA[r][kw * 4] = v;
        }
        // prefetch gi for epilogue (normal loads, L2/L3)
        unsigned gi_r = 0, gi_z = 0, gi_n = 0;
        if (ep) {
            size_t grow = ((size_t)step * 512 + tbase + et) * 1536;
            const unsigned* gp = (const unsigned*)gi_bf;
            gi_r = gp[(grow + cbase + ec) >> 1];
            gi_z = gp[(grow + 512 + cbase + ec) >> 1];
            gi_n = gp[(grow + 1024 + cbase + ec) >> 1];
        }
        __syncthreads();

        // ---- gh = h @ whh_slice : one 16x16 tile per wave, K=512 ----
        f32x4 accA = {0.f, 0.f, 0.f, 0.f}, accB = accA;
#pragma unroll
        for (int kk = 0; kk < 16; kk += 2) {
            bf16x8 a0 = *(bf16x8*)&lhA[th * 16 + fr][kk * 32 + fo * 8];
            bf16x8 b0 = *(bf16x8*)&lw[ct * 16 + fr][kk * 32 + fo * 8];
            bf16x8 a1 = *(bf16x8*)&lhA[th * 16 + fr][(kk + 1) * 32 + fo * 8];
            bf16x8 b1 = *(bf16x8*)&lw[ct * 16 + fr][(kk + 1) * 32 + fo * 8];
            accA = __builtin_amdgcn_mfma_f32_16x16x32_bf16(a0, b0, accA, 0, 0, 0);
            accB = __builtin_amdgcn_mfma_f32_16x16x32_bf16(a1, b1, accB, 0, 0, 0);
        }
#pragma unroll
        for (int reg = 0; reg < 4; ++reg)
            ghs[th * 16 + fo * 4 + reg][ct * 16 + fr] = accA[reg] + accB[reg];
        __syncthreads();

        // ---- gate math + h update (threads 0..511) ----
        if (ep) {
            float ghr0 = ghs[et][ec],      ghr1 = ghs[et][ec + 1];
            float ghz0 = ghs[et][32 + ec], ghz1 = ghs[et][32 + ec + 1];
            float ghn0 = ghs[et][64 + ec], ghn1 = ghs[et][64 + ec + 1];
            float r0 = sigmoidf_(bf2f((u16)(gi_r & 0xffff)) + ghr0 + bh_r0);
            float r1 = sigmoidf_(bf2f((u16)(gi_r >> 16)) + ghr1 + bh_r1);
            float z0 = sigmoidf_(bf2f((u16)(gi_z & 0xffff)) + ghz0 + bh_z0);
            float z1 = sigmoidf_(bf2f((u16)(gi_z >> 16)) + ghz1 + bh_z1);
            float n0 = tanhf(bf2f((u16)(gi_n & 0xffff)) + r0 * (ghn0 + bh_n0));
            float n1 = tanhf(bf2f((u16)(gi_n >> 16)) + r1 * (ghn1 + bh_n1));
            hreg0 = (1.f - z0) * n0 + z0 * hreg0;
            hreg1 = (1.f - z1) * n1 + z1 * hreg1;
            unsigned packv = (unsigned)f2bf(hreg0) | ((unsigned)f2bf(hreg1) << 16);
            __hip_atomic_store(
                (unsigned*)out_bf + ((((size_t)step * 512 + tbase + et) * 512 + cbase + ec) >> 1),
                packv, __ATOMIC_RELAXED, __HIP_MEMORY_SCOPE_AGENT);
        }
        __syncthreads();   // drains vmcnt: all h stores at L3 before signal

        if (step < 63) {
            if (tid == 0) {
                __hip_atomic_fetch_add(&cnt[tg * 32], 1u,
                                       __ATOMIC_RELAXED, __HIP_MEMORY_SCOPE_AGENT);
                unsigned tgt = 16u * (unsigned)(step + 1);
                while (__hip_atomic_load(&cnt[tg * 32],
                                         __ATOMIC_RELAXED, __HIP_MEMORY_SCOPE_AGENT) < tgt)
                    __builtin_amdgcn_s_sleep(2);
            }
            __syncthreads();
        }
    }
}

// ---------------------------------------------------------------------------
extern "C" void kernel_launch(void* const* d_in, const int* in_sizes, int n_in,
                              void* d_out, int out_size, void* d_ws, size_t ws_size,
                              hipStream_t stream)
{
    const float* state   = (const float*)d_in[0];
    const float* action  = (const float*)d_in[1];
    const float* ae_w1   = (const float*)d_in[2];
    const float* ae_b1   = (const float*)d_in[3];
    const float* ae_w2   = (const float*)d_in[4];
    const float* ae_b2   = (const float*)d_in[5];
    const float* ln2_g   = (const float*)d_in[8];
    const float* ln2_b   = (const float*)d_in[9];
    const float* wv      = (const float*)d_in[14];
    const float* bv      = (const float*)d_in[15];
    const float* wo      = (const float*)d_in[16];
    const float* bo      = (const float*)d_in[17];
    const float* gru_wih = (const float*)d_in[18];
    const float* gru_bih = (const float*)d_in[19];
    const float* gru_whh = (const float*)d_in[20];
    const float* gru_bhh = (const float*)d_in[21];
    const float* mlp_w   = (const float*)d_in[22];
    const float* mlp_b   = (const float*)d_in[23];

    char* ws = (char*)d_ws;
    size_t off = 0;
    auto carve = [&](size_t bytes) -> char* {
        char* p = ws + off; off = (off + bytes + 255) & ~(size_t)255; return p;
    };
    u16*   kv_bf  = (u16*)carve(32768ull * 256 * 2);
    u16*   x_bf   = (u16*)carve(32768ull * 256 * 2);
    u16*   gi_bf  = (u16*)carve(32768ull * 1536 * 2);
    u16*   out_bf = (u16*)carve(32768ull * 512 * 2);
    u16*   WfT    = (u16*)carve(256 * 256 * 2);
    float* bfv    = (float*)carve(256 * 4);
    u16*   wihT   = (u16*)carve(1536 * 256 * 2);
    u16*   whhT   = (u16*)carve(1536 * 512 * 2);
    u16*   mlpT   = (u16*)carve(256 * 512 * 2);
    u16*   w2T    = (u16*)carve(256 * 128 * 2);
    u16*   h0_bf  = (u16*)carve(512 * 512 * 2);
    unsigned* cnt = (unsigned*)carve(16 * 32 * 4);

    hipMemsetAsync(h0_bf, 0, 512 * 512 * 2, stream);
    hipMemsetAsync(cnt, 0, 16 * 32 * 4, stream);

    fuse_wvwo<<<256, 256, 0, stream>>>(wv, wo, bv, bo, WfT, bfv);
    transpose_bf<<<1536, 256, 0, stream>>>(gru_wih, wihT, 256, 1536);
    transpose_bf<<<3072, 256, 0, stream>>>(gru_whh, whhT, 512, 1536);
    transpose_bf<<<512, 256, 0, stream>>>(mlp_w, mlpT, 512, 256);
    transpose_bf<<<128, 256, 0, stream>>>(ae_w2, w2T, 128, 256);

    ae_ln_mfma<<<512, 256, 0, stream>>>(action, ae_w1, ae_b1, w2T, ae_b2,
                                        ln2_g, ln2_b, kv_bf);

    // x = state + kv_in @ Wf + bfv   (bf16 out)
    gemm64<0><<<dim3(512, 4), 256, 0, stream>>>(kv_bf, WfT, bfv, state, x_bf, nullptr, 256, 256);
    // gi = x @ wih + bih             (bf16 out)
    gemm64<1><<<dim3(512, 24), 256, 0, stream>>>(x_bf, wihT, gru_bih, nullptr, gi_bf, nullptr, 1536, 256);

    // GRU: one persistent cooperative kernel, all 64 steps, fence-free sync
    {
        void* args[] = { (void*)&whhT, (void*)&gru_bhh, (void*)&gi_bf,
                         (void*)&h0_bf, (void*)&out_bf, (void*)&cnt };
        hipLaunchCooperativeKernel((const void*)gru_persistent2, dim3(256), dim3(768),
                                   args, 0, stream);
    }

    // states = out @ mlp_w + mlp_b   (f32 out + last-row duplicate)
    gemm64<2><<<dim3(512, 4), 256, 0, stream>>>(out_bf, mlpT, mlp_b, nullptr, nullptr,
                                                (float*)d_out, 256, 512);
}

// Round 5
// 461.328 us; speedup vs baseline: 3.8698x; 1.1070x over previous
//
#include <hip/hip_runtime.h>
#include <hip/hip_bf16.h>

typedef unsigned short u16;
typedef unsigned long long u64;
typedef __attribute__((ext_vector_type(8))) short bf16x8;
typedef __attribute__((ext_vector_type(4))) float f32x4;

static __device__ __forceinline__ u16 f2bf(float f) {
    union { float f; unsigned u; } cv; cv.f = f;
    unsigned u = cv.u;
    unsigned r = u + 0x7FFF + ((u >> 16) & 1);   // round-to-nearest-even
    return (u16)(r >> 16);
}
static __device__ __forceinline__ float bf2f(u16 b) {
    union { unsigned u; float f; } cv; cv.u = ((unsigned)b) << 16;
    return cv.f;
}
static __device__ __forceinline__ float sigmoidf_(float x) {
    return 1.0f / (1.0f + __expf(-x));
}

// ---------------------------------------------------------------------------
// Fuse Wf = wv @ wo (bf16, stored transposed [j][i]) and bfv = bv@wo + bo.
__global__ __launch_bounds__(256) void fuse_wvwo(
    const float* __restrict__ wv, const float* __restrict__ wo,
    const float* __restrict__ bv, const float* __restrict__ bo,
    u16* __restrict__ WfT, float* __restrict__ bfv)
{
    int j = blockIdx.x;
    int i = threadIdx.x;
    float s = 0.f;
    for (int k = 0; k < 256; ++k) s += wv[i * 256 + k] * wo[k * 256 + j];
    WfT[j * 256 + i] = f2bf(s);
    if (i == 0) {
        float t = bo[j];
        for (int k = 0; k < 256; ++k) t += bv[k] * wo[k * 256 + j];
        bfv[j] = t;
    }
}

// dst[n*K + k] = bf16(src[k*N + n])
__global__ __launch_bounds__(256) void transpose_bf(
    const float* __restrict__ src, u16* __restrict__ dst, int K, int N)
{
    long i = (long)blockIdx.x * 256 + threadIdx.x;
    if (i >= (long)K * N) return;
    int n = (int)(i / K), k = (int)(i % K);
    dst[i] = f2bf(src[(long)k * N + n]);
}

// ---------------------------------------------------------------------------
// Fused action-encoder + LayerNorm, MFMA version. 64 positions per block.
__global__ __launch_bounds__(256) void ae_ln_mfma(
    const float* __restrict__ action,
    const float* __restrict__ w1, const float* __restrict__ b1,
    const u16* __restrict__ w2T, const float* __restrict__ b2,
    const float* __restrict__ g, const float* __restrict__ be,
    u16* __restrict__ kvbf)
{
    __shared__ u16 lB[256][136];   // w2T staged; reused as f32 [64][261] later
    __shared__ u16 lA[64][136];    // h1 tile bf16
    int tid = threadIdx.x;
    long base = (long)blockIdx.x * 64;

    for (int idx = tid; idx < 256 * 16; idx += 256) {
        int r = idx >> 4, ch = (idx & 15) * 8;
        *(uint4*)&lB[r][ch] = *(const uint4*)&w2T[r * 128 + ch];
    }
    for (int idx = tid; idx < 8192; idx += 256) {
        int r = idx >> 7, k = idx & 127;
        float a0 = action[(base + r) * 2], a1 = action[(base + r) * 2 + 1];
        float v = fmaf(a1, w1[128 + k], fmaf(a0, w1[k], b1[k]));
        lA[r][k] = f2bf(v > 0.f ? v : 0.f);
    }
    __syncthreads();

    int wv = tid >> 6, l = tid & 63;
    int fr = l & 15, fq = l >> 4;
    f32x4 acc[4][4] = {};
#pragma unroll
    for (int ks = 0; ks < 4; ++ks) {
        bf16x8 a[4], b[4];
#pragma unroll
        for (int mi = 0; mi < 4; ++mi) a[mi] = *(bf16x8*)&lA[mi * 16 + fr][ks * 32 + fq * 8];
#pragma unroll
        for (int ni = 0; ni < 4; ++ni) b[ni] = *(bf16x8*)&lB[wv * 64 + ni * 16 + fr][ks * 32 + fq * 8];
#pragma unroll
        for (int mi = 0; mi < 4; ++mi)
#pragma unroll
            for (int ni = 0; ni < 4; ++ni)
                acc[mi][ni] = __builtin_amdgcn_mfma_f32_16x16x32_bf16(a[mi], b[ni], acc[mi][ni], 0, 0, 0);
    }
    __syncthreads();

    float* e = (float*)&lB[0][0];   // [64][261] f32 scratch
#pragma unroll
    for (int mi = 0; mi < 4; ++mi)
#pragma unroll
        for (int ni = 0; ni < 4; ++ni) {
            int col = wv * 64 + ni * 16 + fr;
            float bb = b2[col];
#pragma unroll
            for (int reg = 0; reg < 4; ++reg)
                e[(mi * 16 + fq * 4 + reg) * 261 + col] = acc[mi][ni][reg] + bb;
        }
    __syncthreads();

    int t = tid >> 2, sub = tid & 3;
    float s = 0.f, ss = 0.f;
#pragma unroll
    for (int i = 0; i < 64; ++i) {
        float v = e[t * 261 + sub + i * 4];
        s += v; ss += v * v;
    }
    s += __shfl_xor(s, 1); ss += __shfl_xor(ss, 1);
    s += __shfl_xor(s, 2); ss += __shfl_xor(ss, 2);
    float m = s * (1.f / 256.f);
    float var = ss * (1.f / 256.f) - m * m;
    float rs = rsqrtf(var + 1e-5f);
#pragma unroll
    for (int i8 = 0; i8 < 8; ++i8) {
        u16 pack[8];
#pragma unroll
        for (int j = 0; j < 8; ++j) {
            int col = sub * 64 + i8 * 8 + j;
            float v = (e[t * 261 + col] - m) * rs * g[col] + be[col];
            pack[j] = f2bf(v);
        }
        *(uint4*)&kvbf[(base + t) * 256 + sub * 64 + i8 * 8] = *(uint4*)pack;
    }
}

// ---------------------------------------------------------------------------
// Generic 64x64-tile bf16 GEMM:  C = A[M,K] @ BT[N,K]^T  (+bias[col]) (+modes)
template <int MODE>
__global__ __launch_bounds__(256) void gemm64(
    const u16* __restrict__ A, const u16* __restrict__ BT,
    const float* __restrict__ bias, const float* __restrict__ resid,
    u16* __restrict__ outBf, float* __restrict__ outF,
    int N, int K)
{
    __shared__ u16 lA[64][40];
    __shared__ u16 lB[64][40];
    int tid = threadIdx.x;
    int bm = blockIdx.x * 64, bn = blockIdx.y * 64;
    int srow = tid >> 2, sch = (tid & 3) * 8;

    f32x4 acc[2][2] = {};
    int w = tid >> 6, l = tid & 63;
    int wr = (w >> 1) * 32, wc = (w & 1) * 32;
    int fr = l & 15, fk = (l >> 4) * 8;

    for (int k0 = 0; k0 < K; k0 += 32) {
        *(uint4*)&lA[srow][sch] = *(const uint4*)&A[(long)(bm + srow) * K + k0 + sch];
        *(uint4*)&lB[srow][sch] = *(const uint4*)&BT[(long)(bn + srow) * K + k0 + sch];
        __syncthreads();
        bf16x8 a0 = *(bf16x8*)&lA[wr + fr][fk];
        bf16x8 a1 = *(bf16x8*)&lA[wr + 16 + fr][fk];
        bf16x8 b0 = *(bf16x8*)&lB[wc + fr][fk];
        bf16x8 b1 = *(bf16x8*)&lB[wc + 16 + fr][fk];
        acc[0][0] = __builtin_amdgcn_mfma_f32_16x16x32_bf16(a0, b0, acc[0][0], 0, 0, 0);
        acc[0][1] = __builtin_amdgcn_mfma_f32_16x16x32_bf16(a0, b1, acc[0][1], 0, 0, 0);
        acc[1][0] = __builtin_amdgcn_mfma_f32_16x16x32_bf16(a1, b0, acc[1][0], 0, 0, 0);
        acc[1][1] = __builtin_amdgcn_mfma_f32_16x16x32_bf16(a1, b1, acc[1][1], 0, 0, 0);
        __syncthreads();
    }

#pragma unroll
    for (int mi = 0; mi < 2; ++mi)
#pragma unroll
        for (int ni = 0; ni < 2; ++ni) {
            int c = bn + wc + ni * 16 + fr;
            float bz = bias[c];
#pragma unroll
            for (int reg = 0; reg < 4; ++reg) {
                int r = bm + wr + mi * 16 + (l >> 4) * 4 + reg;
                float v = acc[mi][ni][reg] + bz;
                if constexpr (MODE == 0) {
                    v += resid[(long)r * N + c];
                    outBf[(long)r * N + c] = f2bf(v);
                } else if constexpr (MODE == 1) {
                    outBf[(long)r * N + c] = f2bf(v);
                } else {
                    outF[(long)r * N + c] = v;
                    if ((r & 511) == 511) outF[8388608 + (long)(r >> 9) * N + c] = v;
                }
            }
        }
}

// ---------------------------------------------------------------------------
// Persistent GRU v3. 256 blocks = 16 t-groups x 16 col-blocks, 768 threads
// (12 waves). whh fragments in REGISTERS (step-invariant, 64 VGPR/lane).
// Wave = (tpos, gate, khalf): computes gh^T tile via mfma(whh, h) so each
// lane holds 4 consecutive cols. Only the h tile (32KB) is LDS-staged, with
// XOR swizzle (bank-conflict-free). gi prefetched during the sync poll.
// h exchange via agent-scope relaxed atomics; no cache-flushing fences.
__global__ __launch_bounds__(768, 1) void gru_persistent3(
    const u16* __restrict__ whhT, const float* __restrict__ bhh,
    const u16* __restrict__ gi_bf, const u16* __restrict__ h0_bf,
    u16* __restrict__ out_bf, unsigned* __restrict__ cnt)
{
    __shared__ u64 lh64[4096];             // swizzled h tile [32][512] bf16, 32KB
    __shared__ float ghs[2][3][32][36];    // [khalf][gate][t_loc][c_loc] 27.6KB
    u16* lh = (u16*)lh64;

    int tid = threadIdx.x;
    int bid = blockIdx.x;
    int tg = bid >> 4, cb = bid & 15;
    int tbase = tg * 32, cbase = cb * 32;

    int w = tid >> 6, l = tid & 63;
    int fr = l & 15, fo = l >> 4;
    int w6 = w % 6;
    int tpos = w6 & 1, gate = w6 >> 1, kh = w / 6;

    // whh A-fragments -> registers, once (a[cpos][kk])
    bf16x8 a[2][8];
#pragma unroll
    for (int cpos = 0; cpos < 2; ++cpos) {
        const u16* wp = whhT + ((size_t)(gate << 9) + cbase + cpos * 16 + fr) * 512
                        + kh * 256 + fo * 8;
#pragma unroll
        for (int kk = 0; kk < 8; ++kk)
            a[cpos][kk] = *(const bf16x8*)(wp + kk * 32);
    }

    // epilogue: threads 0..511 own (t = et, cols ec, ec+1); h carry in regs
    int et = tid >> 4, ec = (tid & 15) * 2;
    bool ep = tid < 512;
    float hreg0 = 0.f, hreg1 = 0.f;
    float bh_r0 = 0, bh_r1 = 0, bh_z0 = 0, bh_z1 = 0, bh_n0 = 0, bh_n1 = 0;
    if (ep) {
        bh_r0 = bhh[cbase + ec];        bh_r1 = bhh[cbase + ec + 1];
        bh_z0 = bhh[512 + cbase + ec];  bh_z1 = bhh[512 + cbase + ec + 1];
        bh_n0 = bhh[1024 + cbase + ec]; bh_n1 = bhh[1024 + cbase + ec + 1];
    }

    // gi prefetch for step 0
    const unsigned* gp = (const unsigned*)gi_bf;
    unsigned gi_r = 0, gi_z = 0, gi_n = 0;
    if (ep) {
        size_t grow = (size_t)(tbase + et) * 1536;
        gi_r = gp[(grow + cbase + ec) >> 1];
        gi_z = gp[(grow + 512 + cbase + ec) >> 1];
        gi_n = gp[(grow + 1024 + cbase + ec) >> 1];
    }

    for (int step = 0; step < 64; ++step) {
        // ---- stage this t-group's h rows into swizzled LDS ----
        const u64* hb64 = (const u64*)(step ? out_bf + (size_t)(step - 1) * 262144
                                           : h0_bf);
        for (int idx = tid; idx < 4096; idx += 768) {
            int r = idx >> 7, kw = idx & 127;
            u64 v = __hip_atomic_load(hb64 + (size_t)(tbase + r) * 128 + kw,
                                      __ATOMIC_RELAXED, __HIP_MEMORY_SCOPE_AGENT);
            lh64[r * 128 + (kw ^ ((r & 7) << 1))] = v;
        }
        __syncthreads();

        // ---- gh^T = whh_slice @ h^T : 16 MFMAs per wave, B from LDS ----
        f32x4 acc0 = {0.f, 0.f, 0.f, 0.f}, acc1 = acc0;
        int row = tpos * 16 + fr;
        int kb = kh * 256 + fo * 8;
#pragma unroll
        for (int kk = 0; kk < 8; ++kk) {
            bf16x8 b = *(bf16x8*)&lh[row * 512 + ((kb + kk * 32) ^ ((row & 7) << 3))];
            acc0 = __builtin_amdgcn_mfma_f32_16x16x32_bf16(a[0][kk], b, acc0, 0, 0, 0);
            acc1 = __builtin_amdgcn_mfma_f32_16x16x32_bf16(a[1][kk], b, acc1, 0, 0, 0);
        }
        // D: row = c_loc = cpos*16 + fo*4 + reg, col = t_loc = row(var above)
        *(f32x4*)&ghs[kh][gate][row][fo * 4] = acc0;
        *(f32x4*)&ghs[kh][gate][row][16 + fo * 4] = acc1;
        __syncthreads();

        // ---- gate math + h update (threads 0..511), gi already in regs ----
        if (ep) {
            float ghr0 = ghs[0][0][et][ec] + ghs[1][0][et][ec];
            float ghr1 = ghs[0][0][et][ec + 1] + ghs[1][0][et][ec + 1];
            float ghz0 = ghs[0][1][et][ec] + ghs[1][1][et][ec];
            float ghz1 = ghs[0][1][et][ec + 1] + ghs[1][1][et][ec + 1];
            float ghn0 = ghs[0][2][et][ec] + ghs[1][2][et][ec];
            float ghn1 = ghs[0][2][et][ec + 1] + ghs[1][2][et][ec + 1];
            float r0 = sigmoidf_(bf2f((u16)(gi_r & 0xffff)) + ghr0 + bh_r0);
            float r1 = sigmoidf_(bf2f((u16)(gi_r >> 16)) + ghr1 + bh_r1);
            float z0 = sigmoidf_(bf2f((u16)(gi_z & 0xffff)) + ghz0 + bh_z0);
            float z1 = sigmoidf_(bf2f((u16)(gi_z >> 16)) + ghz1 + bh_z1);
            float n0 = tanhf(bf2f((u16)(gi_n & 0xffff)) + r0 * (ghn0 + bh_n0));
            float n1 = tanhf(bf2f((u16)(gi_n >> 16)) + r1 * (ghn1 + bh_n1));
            hreg0 = (1.f - z0) * n0 + z0 * hreg0;
            hreg1 = (1.f - z1) * n1 + z1 * hreg1;
            unsigned packv = (unsigned)f2bf(hreg0) | ((unsigned)f2bf(hreg1) << 16);
            __hip_atomic_store(
                (unsigned*)out_bf + ((((size_t)step * 512 + tbase + et) * 512 + cbase + ec) >> 1),
                packv, __ATOMIC_RELAXED, __HIP_MEMORY_SCOPE_AGENT);
        }
        __syncthreads();   // drains vmcnt: h stores globally visible before signal

        if (step < 63) {
            // prefetch next step's gi while the t-group barrier settles
            if (ep) {
                size_t grow = ((size_t)(step + 1) * 512 + tbase + et) * 1536;
                gi_r = gp[(grow + cbase + ec) >> 1];
                gi_z = gp[(grow + 512 + cbase + ec) >> 1];
                gi_n = gp[(grow + 1024 + cbase + ec) >> 1];
            }
            if (tid == 0) {
                __hip_atomic_fetch_add(&cnt[tg * 32], 1u,
                                       __ATOMIC_RELAXED, __HIP_MEMORY_SCOPE_AGENT);
                unsigned tgt = 16u * (unsigned)(step + 1);
                while (__hip_atomic_load(&cnt[tg * 32],
                                         __ATOMIC_RELAXED, __HIP_MEMORY_SCOPE_AGENT) < tgt)
                    __builtin_amdgcn_s_sleep(2);
            }
            __syncthreads();
        }
    }
}

// ---------------------------------------------------------------------------
extern "C" void kernel_launch(void* const* d_in, const int* in_sizes, int n_in,
                              void* d_out, int out_size, void* d_ws, size_t ws_size,
                              hipStream_t stream)
{
    const float* state   = (const float*)d_in[0];
    const float* action  = (const float*)d_in[1];
    const float* ae_w1   = (const float*)d_in[2];
    const float* ae_b1   = (const float*)d_in[3];
    const float* ae_w2   = (const float*)d_in[4];
    const float* ae_b2   = (const float*)d_in[5];
    const float* ln2_g   = (const float*)d_in[8];
    const float* ln2_b   = (const float*)d_in[9];
    const float* wv      = (const float*)d_in[14];
    const float* bv      = (const float*)d_in[15];
    const float* wo      = (const float*)d_in[16];
    const float* bo      = (const float*)d_in[17];
    const float* gru_wih = (const float*)d_in[18];
    const float* gru_bih = (const float*)d_in[19];
    const float* gru_whh = (const float*)d_in[20];
    const float* gru_bhh = (const float*)d_in[21];
    const float* mlp_w   = (const float*)d_in[22];
    const float* mlp_b   = (const float*)d_in[23];

    char* ws = (char*)d_ws;
    size_t off = 0;
    auto carve = [&](size_t bytes) -> char* {
        char* p = ws + off; off = (off + bytes + 255) & ~(size_t)255; return p;
    };
    u16*   kv_bf  = (u16*)carve(32768ull * 256 * 2);
    u16*   x_bf   = (u16*)carve(32768ull * 256 * 2);
    u16*   gi_bf  = (u16*)carve(32768ull * 1536 * 2);
    u16*   out_bf = (u16*)carve(32768ull * 512 * 2);
    u16*   WfT    = (u16*)carve(256 * 256 * 2);
    float* bfv    = (float*)carve(256 * 4);
    u16*   wihT   = (u16*)carve(1536 * 256 * 2);
    u16*   whhT   = (u16*)carve(1536 * 512 * 2);
    u16*   mlpT   = (u16*)carve(256 * 512 * 2);
    u16*   w2T    = (u16*)carve(256 * 128 * 2);
    u16*   h0_bf  = (u16*)carve(512 * 512 * 2);
    unsigned* cnt = (unsigned*)carve(16 * 32 * 4);

    hipMemsetAsync(h0_bf, 0, 512 * 512 * 2, stream);
    hipMemsetAsync(cnt, 0, 16 * 32 * 4, stream);

    fuse_wvwo<<<256, 256, 0, stream>>>(wv, wo, bv, bo, WfT, bfv);
    transpose_bf<<<1536, 256, 0, stream>>>(gru_wih, wihT, 256, 1536);
    transpose_bf<<<3072, 256, 0, stream>>>(gru_whh, whhT, 512, 1536);
    transpose_bf<<<512, 256, 0, stream>>>(mlp_w, mlpT, 512, 256);
    transpose_bf<<<128, 256, 0, stream>>>(ae_w2, w2T, 128, 256);

    ae_ln_mfma<<<512, 256, 0, stream>>>(action, ae_w1, ae_b1, w2T, ae_b2,
                                        ln2_g, ln2_b, kv_bf);

    // x = state + kv_in @ Wf + bfv   (bf16 out)
    gemm64<0><<<dim3(512, 4), 256, 0, stream>>>(kv_bf, WfT, bfv, state, x_bf, nullptr, 256, 256);
    // gi = x @ wih + bih             (bf16 out)
    gemm64<1><<<dim3(512, 24), 256, 0, stream>>>(x_bf, wihT, gru_bih, nullptr, gi_bf, nullptr, 1536, 256);

    // GRU: one persistent cooperative kernel, all 64 steps
    {
        void* args[] = { (void*)&whhT, (void*)&gru_bhh, (void*)&gi_bf,
                         (void*)&h0_bf, (void*)&out_bf, (void*)&cnt };
        hipLaunchCooperativeKernel((const void*)gru_persistent3, dim3(256), dim3(768),
                                   args, 0, stream);
    }

    // states = out @ mlp_w + mlp_b   (f32 out + last-row duplicate)
    gemm64<2><<<dim3(512, 4), 256, 0, stream>>>(out_bf, mlpT, mlp_b, nullptr, nullptr,
                                                (float*)d_out, 256, 512);
}